// Round 15
// baseline (229.555 us; speedup 1.0000x reference)
//
#include <hip/hip_runtime.h>
#include <hip/hip_bf16.h>
#include <math.h>

#define B 128
#define S 1024
#define H 768
#define NH 8
#define DH 96
#define FUSED 2312
#define KCHUNK 128
#define NOUT 544             // 512 hdn1 + 3 pol + 3 aro + pad
#define MD 800               // M buffer row stride (768 + bias col + pad)
#define NZ_NOCTX 13          // z in {0..5, 12..18}
#define NZ_CTX 5             // K=800 in 5 chunks of 160
#define NZTOT 18
#define ASL 8                // aspq slices
#define NSL 8                // flash slices per sample
#define FCH 16               // rows per flash chunk
#define SCALE 0.10206207261596575f  // 1/sqrt(96)
#define GELU_C 0.70710678118654752f

#define MTILES (17 * 25)     // M-GEMM tile jobs (n-tiles x d-tiles)
#define HTILES (NZ_NOCTX * 4 * 17)  // hdn1-noctx tile jobs = 884

__device__ __forceinline__ float dot4(float4 a, float4 b) {
    return a.x * b.x + a.y * b.y + a.z * b.z + a.w * b.w;
}
__device__ __forceinline__ float gelu(float x) {
    return 0.5f * x * (1.0f + erff(x * GELU_C));
}

// row pointer into the virtual [544][2312] W' (va_w1 | pol_w | aro_w | 0)
__device__ __forceinline__ const float* wrow_sel(int n, const float* va_w1,
                                                 const float* pol_w,
                                                 const float* aro_w,
                                                 bool& valid) {
    valid = true;
    if (n < 512) return va_w1 + (size_t)n * FUSED;
    if (n < 515) return pol_w + (size_t)(n - 512) * FUSED;
    if (n < 518) return aro_w + (size_t)(n - 515) * FUSED;
    valid = false;
    return va_w1;
}

// ---------------------------------------------------------------------------
// K1 hetero: bid<1024 -> aspq partial; else -> M-GEMM tile (R14 exact).
// ---------------------------------------------------------------------------
__global__ __launch_bounds__(256) void k1_aspq_m(
        const float* __restrict__ lh,
        const int* __restrict__ sep1,
        const int* __restrict__ sep2,
        const float* __restrict__ va_w1,
        const float* __restrict__ pol_w,
        const float* __restrict__ aro_w,
        const float* __restrict__ out_w,
        const float* __restrict__ out_b,
        float* __restrict__ aspp,
        float* __restrict__ Mbuf) {
    int bid = blockIdx.x, t = threadIdx.x;
    if (bid < B * ASL) {
        if (t >= 192) return;
        int b = bid >> 3, z = bid & 7;
        int s1 = sep1[b], s2 = sep2[b];
        int lo, hi;
        if (s2 > s1 + 1) { lo = s1 + 1; hi = s2; } else { lo = 0; hi = 1; }
        const float* base = lh + ((size_t)b * S) * H + 4 * t;
        float4 a = {0.f, 0.f, 0.f, 0.f};
        for (int s = lo + z; s < hi; s += ASL) {
            float4 r = *(const float4*)(base + (size_t)s * H);
            a.x += r.x; a.y += r.y; a.z += r.z; a.w += r.w;
        }
        *(float4*)(aspp + (size_t)z * (B * H) + b * H + 4 * t) = a;
        return;
    }
    // ---- M-GEMM tile ----
    int j = bid - B * ASL;            // 0..424
    int n0 = (j / 25) * 32, d0 = (j % 25) * 32;
    __shared__ float As[32][33];
    __shared__ float Ws[32][33];
    int tx = t & 31, ty = t >> 5;
    int lr = t >> 3, lc = (t & 7) * 4;
    float acc[4] = {0.f, 0.f, 0.f, 0.f};
    for (int k0 = 0; k0 < H; k0 += 32) {
        {
            int n = n0 + lr;
            bool valid;
            const float* wr = wrow_sel(n, va_w1, pol_w, aro_w, valid);
            float4 a = {0.f, 0.f, 0.f, 0.f};
            if (valid) a = *(const float4*)(wr + H + k0 + lc);
            As[lr][lc] = a.x; As[lr][lc + 1] = a.y;
            As[lr][lc + 2] = a.z; As[lr][lc + 3] = a.w;
        }
        {
            int c = k0 + lr;
            float4 w;
            if (d0 < H) {
                w = *(const float4*)(out_w + (size_t)c * H + d0 + lc);
            } else {
                w.x = (lc == 0) ? out_b[c] : 0.f;
                w.y = 0.f; w.z = 0.f; w.w = 0.f;
            }
            Ws[lc][lr] = w.x; Ws[lc + 1][lr] = w.y;
            Ws[lc + 2][lr] = w.z; Ws[lc + 3][lr] = w.w;
        }
        __syncthreads();
#pragma unroll
        for (int kk = 0; kk < 32; ++kk) {
            float wv = Ws[tx][kk];
#pragma unroll
            for (int i = 0; i < 4; ++i)
                acc[i] += As[ty + 8 * i][kk] * wv;
        }
        __syncthreads();
    }
#pragma unroll
    for (int i = 0; i < 4; ++i)
        Mbuf[(size_t)(n0 + ty + 8 * i) * MD + d0 + tx] = acc[i];
}

// ---------------------------------------------------------------------------
// K2: qu (R14 exact) — merge aspq partials; q_h; U = q_h @ wk_h (float4).
// ---------------------------------------------------------------------------
__global__ void qu_kernel(const float* __restrict__ aspp,
                          const int* __restrict__ sep1,
                          const int* __restrict__ sep2,
                          const float* __restrict__ wq,
                          const float* __restrict__ bq,
                          const float* __restrict__ wk,
                          float* __restrict__ aspq,
                          float* __restrict__ U) {
    int b = blockIdx.x, h = blockIdx.y, t = threadIdx.x;
    int s1 = sep1[b], s2 = sep2[b];
    int lo, hi;
    if (s2 > s1 + 1) { lo = s1 + 1; hi = s2; } else { lo = 0; hi = 1; }
    float inv = 1.0f / (float)(hi - lo);
    __shared__ float aq[H];
    __shared__ float qh[DH];
    for (int c = t; c < H; c += 256) {
        float a = 0.f;
#pragma unroll
        for (int z = 0; z < ASL; ++z)
            a += aspp[(size_t)z * (B * H) + b * H + c];
        a *= inv;
        aq[c] = a;
        if (h == 0) aspq[b * H + c] = a;
    }
    __syncthreads();
    int wave = t >> 6, lane = t & 63;
#pragma unroll
    for (int i = 0; i < 24; ++i) {
        int d = wave * 24 + i;
        const float* wrow = wq + (size_t)(h * DH + d) * H;
        float a = 0.f;
#pragma unroll
        for (int j = 0; j < H / 64; ++j) a += wrow[lane + 64 * j] * aq[lane + 64 * j];
        for (int off = 32; off; off >>= 1) a += __shfl_xor(a, off);
        if (lane == 0) qh[d] = a + bq[h * DH + d];
    }
    __syncthreads();
    if (t < 192) {
        float4 u = {0.f, 0.f, 0.f, 0.f};
        for (int d = 0; d < DH; ++d) {
            float qd = qh[d];
            float4 w = *(const float4*)(wk + (size_t)(h * DH + d) * H + 4 * t);
            u.x += qd * w.x; u.y += qd * w.y;
            u.z += qd * w.z; u.w += qd * w.w;
        }
        *(float4*)(U + ((size_t)b * NH + h) * H + 4 * t) = u;
    }
}

// ---------------------------------------------------------------------------
// K3 hetero: bid<1024 -> flash with T14 async staging (issue-early/write-late)
//            else     -> hdn1-noctx tile (R14 exact).
// ---------------------------------------------------------------------------
__global__ __launch_bounds__(512) void k3_flash_hdn1(
        const float* __restrict__ lhg,
        const float* __restrict__ U,
        const int* __restrict__ sep1,
        const float* __restrict__ aspq,
        const float* __restrict__ aro_f,
        const float* __restrict__ ln_g,
        const float* __restrict__ ln_b,
        const float* __restrict__ va_w1,
        const float* __restrict__ pol_w,
        const float* __restrict__ aro_w,
        float* __restrict__ Op,     // [NSL][B][NH][H]
        float* __restrict__ mlb,    // [NSL][B][NH][2]
        float* __restrict__ hdn1p) {// [NZTOT][B][NOUT]
    __shared__ float smem[FCH * H];   // 48 KB (overlaid)
    int bid = blockIdx.x, t = threadIdx.x;

    if (bid < B * NSL) {
        int b = bid >> 3, z = bid & 7;
        int wave = t >> 6, lane = t & 63;
        int s1 = sep1[b];
        int tlo = (s1 > 1) ? 1 : 0;
        int thi = (s1 > 1) ? s1 : 1;
        int span = thi - tlo;
        int nrows = (span > z) ? ((span - z - 1) / NSL + 1) : 0;
        float (*lhs)[H] = (float(*)[H])smem;

        const float4* Uh = (const float4*)(U + ((size_t)b * NH + wave) * H);
        float4 u0 = Uh[lane], u1 = Uh[lane + 64], u2 = Uh[lane + 128];
        float4 O0 = {0.f, 0.f, 0.f, 0.f}, O1 = O0, O2 = O0;
        float m = -1e30f, l = 0.f;

        if (nrows > 0) {
            int nchunks = (nrows + FCH - 1) / FCH;
            const float* lb = lhg + (size_t)b * S * H;
            float4 st0, st1, st2, st3, st4, st5;
            // element mapping: e = t + 512*k -> row e/192, col4 e%192
#define FLASH_LOAD(J0)                                                        \
            {                                                                 \
                int e, r, c4, rl, sg;                                         \
                e = t;          r = e / 192; c4 = e % 192; rl = (J0) + r;     \
                sg = (rl < nrows) ? (tlo + z + NSL * rl) : (tlo + z);         \
                st0 = ((const float4*)(lb + (size_t)sg * H))[c4];             \
                e = t + 512;    r = e / 192; c4 = e % 192; rl = (J0) + r;     \
                sg = (rl < nrows) ? (tlo + z + NSL * rl) : (tlo + z);         \
                st1 = ((const float4*)(lb + (size_t)sg * H))[c4];             \
                e = t + 1024;   r = e / 192; c4 = e % 192; rl = (J0) + r;     \
                sg = (rl < nrows) ? (tlo + z + NSL * rl) : (tlo + z);         \
                st2 = ((const float4*)(lb + (size_t)sg * H))[c4];             \
                e = t + 1536;   r = e / 192; c4 = e % 192; rl = (J0) + r;     \
                sg = (rl < nrows) ? (tlo + z + NSL * rl) : (tlo + z);         \
                st3 = ((const float4*)(lb + (size_t)sg * H))[c4];             \
                e = t + 2048;   r = e / 192; c4 = e % 192; rl = (J0) + r;     \
                sg = (rl < nrows) ? (tlo + z + NSL * rl) : (tlo + z);         \
                st4 = ((const float4*)(lb + (size_t)sg * H))[c4];             \
                e = t + 2560;   r = e / 192; c4 = e % 192; rl = (J0) + r;     \
                sg = (rl < nrows) ? (tlo + z + NSL * rl) : (tlo + z);         \
                st5 = ((const float4*)(lb + (size_t)sg * H))[c4];             \
            }
#define FLASH_STORE()                                                         \
            {                                                                 \
                int e, r, c4;                                                 \
                e = t;          r = e / 192; c4 = e % 192;                    \
                ((float4*)lhs[r])[c4] = st0;                                  \
                e = t + 512;    r = e / 192; c4 = e % 192;                    \
                ((float4*)lhs[r])[c4] = st1;                                  \
                e = t + 1024;   r = e / 192; c4 = e % 192;                    \
                ((float4*)lhs[r])[c4] = st2;                                  \
                e = t + 1536;   r = e / 192; c4 = e % 192;                    \
                ((float4*)lhs[r])[c4] = st3;                                  \
                e = t + 2048;   r = e / 192; c4 = e % 192;                    \
                ((float4*)lhs[r])[c4] = st4;                                  \
                e = t + 2560;   r = e / 192; c4 = e % 192;                    \
                ((float4*)lhs[r])[c4] = st5;                                  \
            }
            // prologue: stage chunk 0
            FLASH_LOAD(0)
            FLASH_STORE()
            __syncthreads();
            for (int ci = 0; ci < nchunks; ++ci) {
                int j0 = ci * FCH;
                int nv = min(FCH, nrows - j0);
                bool more = (ci + 1 < nchunks);
                if (more) FLASH_LOAD(j0 + FCH)   // issue-early (hides under compute)
                for (int r = 0; r < nv; ++r) {
                    const float4* xr = (const float4*)lhs[r];
                    float4 x0 = xr[lane], x1 = xr[lane + 64], x2 = xr[lane + 128];
                    float s = dot4(u0, x0) + dot4(u1, x1) + dot4(u2, x2);
                    for (int off = 32; off; off >>= 1) s += __shfl_xor(s, off);
                    s *= SCALE;
                    if (s <= m) {
                        float p = __expf(s - m);
                        l += p;
                        O0.x += p * x0.x; O0.y += p * x0.y; O0.z += p * x0.z; O0.w += p * x0.w;
                        O1.x += p * x1.x; O1.y += p * x1.y; O1.z += p * x1.z; O1.w += p * x1.w;
                        O2.x += p * x2.x; O2.y += p * x2.y; O2.z += p * x2.z; O2.w += p * x2.w;
                    } else {
                        float c = __expf(m - s);
                        m = s;
                        l = l * c + 1.0f;
                        O0.x = O0.x * c + x0.x; O0.y = O0.y * c + x0.y;
                        O0.z = O0.z * c + x0.z; O0.w = O0.w * c + x0.w;
                        O1.x = O1.x * c + x1.x; O1.y = O1.y * c + x1.y;
                        O1.z = O1.z * c + x1.z; O1.w = O1.w * c + x1.w;
                        O2.x = O2.x * c + x2.x; O2.y = O2.y * c + x2.y;
                        O2.z = O2.z * c + x2.z; O2.w = O2.w * c + x2.w;
                    }
                }
                __syncthreads();      // all waves done reading lhs
                if (more) {
                    FLASH_STORE()     // write-late
                    __syncthreads();  // chunk i+1 visible
                }
            }
#undef FLASH_LOAD
#undef FLASH_STORE
        }
        float4* Ob = (float4*)(Op + (((size_t)z * B + b) * NH + wave) * H);
        Ob[lane] = O0; Ob[lane + 64] = O1; Ob[lane + 128] = O2;
        if (lane == 0) {
            float* ml = mlb + ((size_t)z * B + b) * NH * 2;
            ml[2 * wave]     = m;
            ml[2 * wave + 1] = l;
        }
        return;
    }

    // ---- hdn1-noctx tile (256 active threads; all 512 hit barriers) ----
    int j = bid - B * NSL;            // 0..883
    int z13 = j / 68, rem = j % 68;
    int z = (z13 < 6) ? z13 : z13 + 6;          // {0..5, 12..18}
    int m0 = (rem / 17) * 32, n0 = (rem % 17) * 32;
    int kbase = z * KCHUNK;
    float (*As)[33] = (float(*)[33])smem;
    float (*Ws)[33] = (float(*)[33])(smem + 32 * 33);
    int tx = t & 31, ty = t >> 5;
    int lr = t >> 3, lc = (t & 7) * 4;
    float acc[4] = {0.f, 0.f, 0.f, 0.f};
    bool active = (t < 256);
    for (int k0 = kbase; k0 < kbase + KCHUNK; k0 += 32) {
        if (active) {
            int bb = m0 + lr;
            int k = k0 + lc;
            float4 a;
            if (k < 768) {
                a = *(const float4*)(lhg + (size_t)bb * S * H + k);
            } else if (k < 2304) {   // only aspq region reachable (z>=12)
                a = *(const float4*)(aspq + (size_t)bb * H + (k - 1536));
            } else if (k < FUSED) {
                const float* af = aro_f + bb * 8;
                float mu = 0.f;
#pragma unroll
                for (int jj = 0; jj < 8; ++jj) mu += af[jj];
                mu *= 0.125f;
                float var = 0.f;
#pragma unroll
                for (int jj = 0; jj < 8; ++jj) { float d = af[jj] - mu; var += d * d; }
                var *= 0.125f;
                float rs = rsqrtf(var + 1e-5f);
                int c = k - 2304;
                a.x = (af[c]     - mu) * rs * ln_g[c]     + ln_b[c];
                a.y = (af[c + 1] - mu) * rs * ln_g[c + 1] + ln_b[c + 1];
                a.z = (af[c + 2] - mu) * rs * ln_g[c + 2] + ln_b[c + 2];
                a.w = (af[c + 3] - mu) * rs * ln_g[c + 3] + ln_b[c + 3];
            } else {
                a = {0.f, 0.f, 0.f, 0.f};
            }
            As[lr][lc] = a.x; As[lr][lc + 1] = a.y;
            As[lr][lc + 2] = a.z; As[lr][lc + 3] = a.w;
            int n = n0 + lr;
            int kk = min(k0 + lc, FUSED - 4);
            bool valid;
            const float* wr = wrow_sel(n, va_w1, pol_w, aro_w, valid);
            float4 w = {0.f, 0.f, 0.f, 0.f};
            if (valid) w = *(const float4*)(wr + kk);
            Ws[lr][lc] = w.x; Ws[lr][lc + 1] = w.y;
            Ws[lr][lc + 2] = w.z; Ws[lr][lc + 3] = w.w;
        }
        __syncthreads();
        if (active) {
#pragma unroll
            for (int kk = 0; kk < 32; ++kk) {
                float wv = Ws[tx][kk];
#pragma unroll
                for (int i = 0; i < 4; ++i)
                    acc[i] += As[ty + 8 * i][kk] * wv;
            }
        }
        __syncthreads();
    }
    if (active) {
        int n = n0 + tx;
#pragma unroll
        for (int i = 0; i < 4; ++i) {
            int mm = m0 + ty + 8 * i;
            hdn1p[(size_t)z13 * (B * NOUT) + (size_t)mm * NOUT + n] = acc[i];
        }
    }
}

// ---------------------------------------------------------------------------
// K4: mergectx (R14 exact).
// ---------------------------------------------------------------------------
__global__ void mergectx_kernel(const float* __restrict__ Op,
                                const float* __restrict__ mlb,
                                const float* __restrict__ wv,
                                const float* __restrict__ bv,
                                float* __restrict__ ctx) {
    int b = blockIdx.x, h = blockIdx.y, t = threadIdx.x;
    float M = -1e30f;
#pragma unroll
    for (int z = 0; z < NSL; ++z)
        M = fmaxf(M, mlb[(((size_t)z * B + b) * NH + h) * 2]);
    float wz[NSL], L = 0.f;
#pragma unroll
    for (int z = 0; z < NSL; ++z) {
        const float* ml = mlb + (((size_t)z * B + b) * NH + h) * 2;
        float e = __expf(ml[0] - M);
        wz[z] = e;
        L += e * ml[1];
    }
    float Li = 1.0f / L;
    __shared__ float wsum[H];
    for (int c = t; c < H; c += 256) {
        float a = 0.f;
#pragma unroll
        for (int z = 0; z < NSL; ++z)
            a += wz[z] * Op[(((size_t)z * B + b) * NH + h) * H + c];
        wsum[c] = a * Li;
    }
    __syncthreads();
    int wave = t >> 6, lane = t & 63;
#pragma unroll
    for (int i = 0; i < 24; ++i) {
        int d = wave * 24 + i;
        const float* wrow = wv + (size_t)(h * DH + d) * H;
        float a = 0.f;
#pragma unroll
        for (int j = 0; j < H / 64; ++j) a += wrow[lane + 64 * j] * wsum[lane + 64 * j];
        for (int off = 32; off; off >>= 1) a += __shfl_xor(a, off);
        if (lane == 0) ctx[b * H + h * DH + d] = a + bv[h * DH + d];
    }
}

// ---------------------------------------------------------------------------
// K5: hdn1-ctx GEMM (R14 exact).
// ---------------------------------------------------------------------------
__global__ __launch_bounds__(256) void k5_hdn1ctx(
        const float* __restrict__ ctx,
        const float* __restrict__ Mbuf,
        float* __restrict__ hdn1p) {
    int z = blockIdx.z;
    int n0 = blockIdx.x * 32, m0 = blockIdx.y * 32;
    int kbase = z * 160;
    __shared__ float As[32][33];
    __shared__ float Ws[32][33];
    int t = threadIdx.x;
    int tx = t & 31, ty = t >> 5;
    int lr = t >> 3, lc = (t & 7) * 4;
    float acc[4] = {0.f, 0.f, 0.f, 0.f};
    for (int k0 = kbase; k0 < kbase + 160; k0 += 32) {
        {
            int bb = m0 + lr;
            int k = k0 + lc;
            float4 a;
            if (k < 768)      a = *(const float4*)(ctx + (size_t)bb * H + k);
            else if (k == 768) a = {1.f, 0.f, 0.f, 0.f};
            else              a = {0.f, 0.f, 0.f, 0.f};
            As[lr][lc] = a.x; As[lr][lc + 1] = a.y;
            As[lr][lc + 2] = a.z; As[lr][lc + 3] = a.w;
        }
        {
            float4 w = *(const float4*)(Mbuf + (size_t)(n0 + lr) * MD + k0 + lc);
            Ws[lr][lc] = w.x; Ws[lr][lc + 1] = w.y;
            Ws[lr][lc + 2] = w.z; Ws[lr][lc + 3] = w.w;
        }
        __syncthreads();
#pragma unroll
        for (int kk = 0; kk < 32; ++kk) {
            float wv = Ws[tx][kk];
#pragma unroll
            for (int i = 0; i < 4; ++i)
                acc[i] += As[ty + 8 * i][kk] * wv;
        }
        __syncthreads();
    }
    int n = n0 + tx;
#pragma unroll
    for (int i = 0; i < 4; ++i) {
        int mm = m0 + ty + 8 * i;
        hdn1p[(size_t)(NZ_NOCTX + z) * (B * NOUT) + (size_t)mm * NOUT + n] = acc[i];
    }
}

// ---------------------------------------------------------------------------
// K6: mlp2 (R14 exact).
// ---------------------------------------------------------------------------
__global__ __launch_bounds__(512) void mlp2_kernel(
        const float* __restrict__ hdn1p,
        const float* __restrict__ va_b1,
        const float* __restrict__ va_w2,
        const float* __restrict__ va_b2,
        const float* __restrict__ va_w3,
        const float* __restrict__ va_b3,
        const float* __restrict__ pol_b,
        const float* __restrict__ aro_b,
        float* __restrict__ out) {
    int b = blockIdx.x, t = threadIdx.x;
    int wave = t >> 6, lane = t & 63;
    __shared__ float hsS[512];
    __shared__ float h2S[128];
    {
        float s = 0.f;
#pragma unroll
        for (int z = 0; z < NZTOT; ++z)
            s += hdn1p[(size_t)z * (B * NOUT) + (size_t)b * NOUT + t];
        hsS[t] = gelu(s + va_b1[t]);
    }
    if (t < 6) {
        float s = 0.f;
#pragma unroll
        for (int z = 0; z < NZTOT; ++z)
            s += hdn1p[(size_t)z * (B * NOUT) + (size_t)b * NOUT + 512 + t];
        if (t < 3) out[256 + b * 3 + t]       = s + pol_b[t];
        else       out[640 + b * 3 + (t - 3)] = s + aro_b[t - 3];
    }
    __syncthreads();
#pragma unroll
    for (int i = 0; i < 16; ++i) {
        int n = wave * 16 + i;
        float a = 0.f;
#pragma unroll
        for (int j = 0; j < 8; ++j) {
            int k = lane + 64 * j;
            a += hsS[k] * va_w2[(size_t)n * 512 + k];
        }
        for (int off = 32; off; off >>= 1) a += __shfl_xor(a, off);
        if (lane == 0) h2S[n] = gelu(a + va_b2[n]);
    }
    __syncthreads();
    if (wave < 2) {
        float a = h2S[lane] * va_w3[wave * 128 + lane]
                + h2S[lane + 64] * va_w3[wave * 128 + lane + 64];
        for (int off = 32; off; off >>= 1) a += __shfl_xor(a, off);
        if (lane == 0) out[b * 2 + wave] = a + va_b3[wave];
    }
}

// ---------------------------------------------------------------------------
extern "C" void kernel_launch(void* const* d_in, const int* in_sizes, int n_in,
                              void* d_out, int out_size, void* d_ws, size_t ws_size,
                              hipStream_t stream) {
    const float* lh    = (const float*)d_in[0];
    const float* aro_f = (const float*)d_in[1];
    const int*   sep1  = (const int*)d_in[2];
    const int*   sep2  = (const int*)d_in[3];
    const float* in_w  = (const float*)d_in[4];
    const float* in_b  = (const float*)d_in[5];
    const float* out_w = (const float*)d_in[6];
    const float* out_b = (const float*)d_in[7];
    const float* ln_g  = (const float*)d_in[8];
    const float* ln_b  = (const float*)d_in[9];
    const float* va_w1 = (const float*)d_in[10];
    const float* va_b1 = (const float*)d_in[11];
    const float* va_w2 = (const float*)d_in[12];
    const float* va_b2 = (const float*)d_in[13];
    const float* va_w3 = (const float*)d_in[14];
    const float* va_b3 = (const float*)d_in[15];
    const float* pol_w = (const float*)d_in[16];
    const float* pol_b = (const float*)d_in[17];
    const float* aro_w = (const float*)d_in[18];
    const float* aro_b = (const float*)d_in[19];
    float* out = (float*)d_out;

    float* ws = (float*)d_ws;
    float* aspp   = ws;                              // ASL*B*H
    float* aspq   = aspp + ASL * B * H;              // B*H
    float* Ubuf   = aspq + B * H;                    // B*NH*H
    float* Opb    = Ubuf + B * NH * H;               // NSL*B*NH*H
    float* mlbuf  = Opb + (size_t)NSL * B * NH * H;  // NSL*B*NH*2
    float* ctx    = mlbuf + NSL * B * NH * 2;        // B*H
    float* Mbuf   = ctx + B * H;                     // 544*MD
    float* hdn1p  = Mbuf + NOUT * MD;                // 18*B*NOUT

    const float* wq = in_w;
    const float* wk = in_w + H * H;
    const float* wv = in_w + 2 * H * H;
    const float* bq = in_b;
    const float* bv = in_b + 2 * H;

    // K1: aspq partials + M = W'_mid @ [out_w | out_b] (hetero)
    k1_aspq_m<<<B * ASL + MTILES, 256, 0, stream>>>(
        lh, sep1, sep2, va_w1, pol_w, aro_w, out_w, out_b, aspp, Mbuf);
    // K2: qu
    qu_kernel<<<dim3(B, NH), 256, 0, stream>>>(aspp, sep1, sep2, wq, bq, wk,
                                               aspq, Ubuf);
    // K3: flash (T14 async-stage) + hdn1-noctx tiles (hetero)
    k3_flash_hdn1<<<B * NSL + HTILES, 512, 0, stream>>>(
        lh, Ubuf, sep1, aspq, aro_f, ln_g, ln_b,
        va_w1, pol_w, aro_w, Opb, mlbuf, hdn1p);
    // K4: mergectx
    mergectx_kernel<<<dim3(B, NH), 256, 0, stream>>>(Opb, mlbuf, wv, bv, ctx);
    // K5: hdn1-ctx via M (K=800, split 5)
    k5_hdn1ctx<<<dim3(17, 4, NZ_CTX), 256, 0, stream>>>(ctx, Mbuf, hdn1p);
    // K6: mlp2
    mlp2_kernel<<<B, 512, 0, stream>>>(hdn1p, va_b1, va_w2, va_b2,
                                       va_w3, va_b3, pol_b, aro_b, out);
}

// Round 16
// 220.380 us; speedup vs baseline: 1.0416x; 1.0416x over previous
//
#include <hip/hip_runtime.h>
#include <hip/hip_bf16.h>
#include <math.h>

#define B 128
#define S 1024
#define H 768
#define NH 8
#define DH 96
#define FUSED 2312
#define KCHUNK 128
#define NOUT 544             // 512 hdn1 + 3 pol + 3 aro + pad
#define MD 800               // M buffer row stride (768 + bias col + pad)
#define NZ_NOCTX 13          // z in {0..5, 12..18}
#define NZ_CTX 5             // K=800 in 5 chunks of 160
#define NZTOT 18
#define ASL 8                // aspq slices
#define NSL 8                // flash slices per sample
#define FCH 16               // rows per flash chunk
#define SCALE 0.10206207261596575f  // 1/sqrt(96)
#define GELU_C 0.70710678118654752f

#define MTILES (17 * 25)     // M-GEMM tile jobs (n-tiles x d-tiles)
#define HTILES (NZ_NOCTX * 4 * 17)  // hdn1-noctx tile jobs = 884

__device__ __forceinline__ float dot4(float4 a, float4 b) {
    return a.x * b.x + a.y * b.y + a.z * b.z + a.w * b.w;
}
__device__ __forceinline__ float gelu(float x) {
    return 0.5f * x * (1.0f + erff(x * GELU_C));
}

// row pointer into the virtual [544][2312] W' (va_w1 | pol_w | aro_w | 0)
__device__ __forceinline__ const float* wrow_sel(int n, const float* va_w1,
                                                 const float* pol_w,
                                                 const float* aro_w,
                                                 bool& valid) {
    valid = true;
    if (n < 512) return va_w1 + (size_t)n * FUSED;
    if (n < 515) return pol_w + (size_t)(n - 512) * FUSED;
    if (n < 518) return aro_w + (size_t)(n - 515) * FUSED;
    valid = false;
    return va_w1;
}

// ---------------------------------------------------------------------------
// K1 hetero: bid<1024 -> aspq partial; else -> M-GEMM tile (R14 exact).
// ---------------------------------------------------------------------------
__global__ __launch_bounds__(256) void k1_aspq_m(
        const float* __restrict__ lh,
        const int* __restrict__ sep1,
        const int* __restrict__ sep2,
        const float* __restrict__ va_w1,
        const float* __restrict__ pol_w,
        const float* __restrict__ aro_w,
        const float* __restrict__ out_w,
        const float* __restrict__ out_b,
        float* __restrict__ aspp,
        float* __restrict__ Mbuf) {
    int bid = blockIdx.x, t = threadIdx.x;
    if (bid < B * ASL) {
        if (t >= 192) return;
        int b = bid >> 3, z = bid & 7;
        int s1 = sep1[b], s2 = sep2[b];
        int lo, hi;
        if (s2 > s1 + 1) { lo = s1 + 1; hi = s2; } else { lo = 0; hi = 1; }
        const float* base = lh + ((size_t)b * S) * H + 4 * t;
        float4 a = {0.f, 0.f, 0.f, 0.f};
        for (int s = lo + z; s < hi; s += ASL) {
            float4 r = *(const float4*)(base + (size_t)s * H);
            a.x += r.x; a.y += r.y; a.z += r.z; a.w += r.w;
        }
        *(float4*)(aspp + (size_t)z * (B * H) + b * H + 4 * t) = a;
        return;
    }
    // ---- M-GEMM tile ----
    int j = bid - B * ASL;            // 0..424
    int n0 = (j / 25) * 32, d0 = (j % 25) * 32;
    __shared__ float As[32][33];
    __shared__ float Ws[32][33];
    int tx = t & 31, ty = t >> 5;
    int lr = t >> 3, lc = (t & 7) * 4;
    float acc[4] = {0.f, 0.f, 0.f, 0.f};
    for (int k0 = 0; k0 < H; k0 += 32) {
        {
            int n = n0 + lr;
            bool valid;
            const float* wr = wrow_sel(n, va_w1, pol_w, aro_w, valid);
            float4 a = {0.f, 0.f, 0.f, 0.f};
            if (valid) a = *(const float4*)(wr + H + k0 + lc);
            As[lr][lc] = a.x; As[lr][lc + 1] = a.y;
            As[lr][lc + 2] = a.z; As[lr][lc + 3] = a.w;
        }
        {
            int c = k0 + lr;
            float4 w;
            if (d0 < H) {
                w = *(const float4*)(out_w + (size_t)c * H + d0 + lc);
            } else {
                w.x = (lc == 0) ? out_b[c] : 0.f;
                w.y = 0.f; w.z = 0.f; w.w = 0.f;
            }
            Ws[lc][lr] = w.x; Ws[lc + 1][lr] = w.y;
            Ws[lc + 2][lr] = w.z; Ws[lc + 3][lr] = w.w;
        }
        __syncthreads();
#pragma unroll
        for (int kk = 0; kk < 32; ++kk) {
            float wv = Ws[tx][kk];
#pragma unroll
            for (int i = 0; i < 4; ++i)
                acc[i] += As[ty + 8 * i][kk] * wv;
        }
        __syncthreads();
    }
#pragma unroll
    for (int i = 0; i < 4; ++i)
        Mbuf[(size_t)(n0 + ty + 8 * i) * MD + d0 + tx] = acc[i];
}

// ---------------------------------------------------------------------------
// K2: qu — T1 XCD placement: grid (NH, B) so linear id = h + 8*b and
// XCD i caches only head i's wq/wk slices (590 KB, L2-resident).
// Body otherwise R14 exact.
// ---------------------------------------------------------------------------
__global__ void qu_kernel(const float* __restrict__ aspp,
                          const int* __restrict__ sep1,
                          const int* __restrict__ sep2,
                          const float* __restrict__ wq,
                          const float* __restrict__ bq,
                          const float* __restrict__ wk,
                          float* __restrict__ aspq,
                          float* __restrict__ U) {
    int h = blockIdx.x, b = blockIdx.y, t = threadIdx.x;
    int s1 = sep1[b], s2 = sep2[b];
    int lo, hi;
    if (s2 > s1 + 1) { lo = s1 + 1; hi = s2; } else { lo = 0; hi = 1; }
    float inv = 1.0f / (float)(hi - lo);
    __shared__ float aq[H];
    __shared__ float qh[DH];
    for (int c = t; c < H; c += 256) {
        float a = 0.f;
#pragma unroll
        for (int z = 0; z < ASL; ++z)
            a += aspp[(size_t)z * (B * H) + b * H + c];
        a *= inv;
        aq[c] = a;
        if (h == 0) aspq[b * H + c] = a;
    }
    __syncthreads();
    int wave = t >> 6, lane = t & 63;
#pragma unroll
    for (int i = 0; i < 24; ++i) {
        int d = wave * 24 + i;
        const float* wrow = wq + (size_t)(h * DH + d) * H;
        float a = 0.f;
#pragma unroll
        for (int j = 0; j < H / 64; ++j) a += wrow[lane + 64 * j] * aq[lane + 64 * j];
        for (int off = 32; off; off >>= 1) a += __shfl_xor(a, off);
        if (lane == 0) qh[d] = a + bq[h * DH + d];
    }
    __syncthreads();
    if (t < 192) {
        float4 u = {0.f, 0.f, 0.f, 0.f};
        for (int d = 0; d < DH; ++d) {
            float qd = qh[d];
            float4 w = *(const float4*)(wk + (size_t)(h * DH + d) * H + 4 * t);
            u.x += qd * w.x; u.y += qd * w.y;
            u.z += qd * w.z; u.w += qd * w.w;
        }
        *(float4*)(U + ((size_t)b * NH + h) * H + 4 * t) = u;
    }
}

// ---------------------------------------------------------------------------
// K3 hetero: bid<1024 -> flash (R14 single-buffered body, proven);
//            else     -> hdn1-noctx tile (R14 exact).
// ---------------------------------------------------------------------------
__global__ __launch_bounds__(512) void k3_flash_hdn1(
        const float* __restrict__ lhg,
        const float* __restrict__ U,
        const int* __restrict__ sep1,
        const float* __restrict__ aspq,
        const float* __restrict__ aro_f,
        const float* __restrict__ ln_g,
        const float* __restrict__ ln_b,
        const float* __restrict__ va_w1,
        const float* __restrict__ pol_w,
        const float* __restrict__ aro_w,
        float* __restrict__ Op,     // [NSL][B][NH][H]
        float* __restrict__ mlb,    // [NSL][B][NH][2]
        float* __restrict__ hdn1p) {// [NZTOT][B][NOUT]
    __shared__ float smem[FCH * H];   // 48 KB (overlaid)
    int bid = blockIdx.x, t = threadIdx.x;

    if (bid < B * NSL) {
        int b = bid >> 3, z = bid & 7;
        int wave = t >> 6, lane = t & 63;
        int s1 = sep1[b];
        int tlo = (s1 > 1) ? 1 : 0;
        int thi = (s1 > 1) ? s1 : 1;
        int span = thi - tlo;
        int nrows = (span > z) ? ((span - z - 1) / NSL + 1) : 0;
        float (*lhs)[H] = (float(*)[H])smem;

        const float4* Uh = (const float4*)(U + ((size_t)b * NH + wave) * H);
        float4 u0 = Uh[lane], u1 = Uh[lane + 64], u2 = Uh[lane + 128];
        float4 O0 = {0.f, 0.f, 0.f, 0.f}, O1 = O0, O2 = O0;
        float m = -1e30f, l = 0.f;
        int rid = t >> 5, cid = t & 31;

        for (int j0 = 0; j0 < nrows; j0 += FCH) {
            int nv = min(FCH, nrows - j0);
            if (rid < nv) {
                int sg = tlo + z + NSL * (j0 + rid);
                const float4* row = (const float4*)(lhg + ((size_t)b * S + sg) * H);
                float4* dst = (float4*)lhs[rid];
#pragma unroll
                for (int k = 0; k < 6; ++k) dst[cid + 32 * k] = row[cid + 32 * k];
            }
            __syncthreads();
            for (int r = 0; r < nv; ++r) {
                const float4* xr = (const float4*)lhs[r];
                float4 x0 = xr[lane], x1 = xr[lane + 64], x2 = xr[lane + 128];
                float s = dot4(u0, x0) + dot4(u1, x1) + dot4(u2, x2);
                for (int off = 32; off; off >>= 1) s += __shfl_xor(s, off);
                s *= SCALE;
                if (s <= m) {
                    float p = __expf(s - m);
                    l += p;
                    O0.x += p * x0.x; O0.y += p * x0.y; O0.z += p * x0.z; O0.w += p * x0.w;
                    O1.x += p * x1.x; O1.y += p * x1.y; O1.z += p * x1.z; O1.w += p * x1.w;
                    O2.x += p * x2.x; O2.y += p * x2.y; O2.z += p * x2.z; O2.w += p * x2.w;
                } else {
                    float c = __expf(m - s);
                    m = s;
                    l = l * c + 1.0f;
                    O0.x = O0.x * c + x0.x; O0.y = O0.y * c + x0.y;
                    O0.z = O0.z * c + x0.z; O0.w = O0.w * c + x0.w;
                    O1.x = O1.x * c + x1.x; O1.y = O1.y * c + x1.y;
                    O1.z = O1.z * c + x1.z; O1.w = O1.w * c + x1.w;
                    O2.x = O2.x * c + x2.x; O2.y = O2.y * c + x2.y;
                    O2.z = O2.z * c + x2.z; O2.w = O2.w * c + x2.w;
                }
            }
            __syncthreads();
        }
        float4* Ob = (float4*)(Op + (((size_t)z * B + b) * NH + wave) * H);
        Ob[lane] = O0; Ob[lane + 64] = O1; Ob[lane + 128] = O2;
        if (lane == 0) {
            float* ml = mlb + ((size_t)z * B + b) * NH * 2;
            ml[2 * wave]     = m;
            ml[2 * wave + 1] = l;
        }
        return;
    }

    // ---- hdn1-noctx tile (256 active threads; all 512 hit barriers) ----
    int j = bid - B * NSL;            // 0..883
    int z13 = j / 68, rem = j % 68;
    int z = (z13 < 6) ? z13 : z13 + 6;          // {0..5, 12..18}
    int m0 = (rem / 17) * 32, n0 = (rem % 17) * 32;
    int kbase = z * KCHUNK;
    float (*As)[33] = (float(*)[33])smem;
    float (*Ws)[33] = (float(*)[33])(smem + 32 * 33);
    int tx = t & 31, ty = t >> 5;
    int lr = t >> 3, lc = (t & 7) * 4;
    float acc[4] = {0.f, 0.f, 0.f, 0.f};
    bool active = (t < 256);
    for (int k0 = kbase; k0 < kbase + KCHUNK; k0 += 32) {
        if (active) {
            int bb = m0 + lr;
            int k = k0 + lc;
            float4 a;
            if (k < 768) {
                a = *(const float4*)(lhg + (size_t)bb * S * H + k);
            } else if (k < 2304) {   // only aspq region reachable (z>=12)
                a = *(const float4*)(aspq + (size_t)bb * H + (k - 1536));
            } else if (k < FUSED) {
                const float* af = aro_f + bb * 8;
                float mu = 0.f;
#pragma unroll
                for (int jj = 0; jj < 8; ++jj) mu += af[jj];
                mu *= 0.125f;
                float var = 0.f;
#pragma unroll
                for (int jj = 0; jj < 8; ++jj) { float d = af[jj] - mu; var += d * d; }
                var *= 0.125f;
                float rs = rsqrtf(var + 1e-5f);
                int c = k - 2304;
                a.x = (af[c]     - mu) * rs * ln_g[c]     + ln_b[c];
                a.y = (af[c + 1] - mu) * rs * ln_g[c + 1] + ln_b[c + 1];
                a.z = (af[c + 2] - mu) * rs * ln_g[c + 2] + ln_b[c + 2];
                a.w = (af[c + 3] - mu) * rs * ln_g[c + 3] + ln_b[c + 3];
            } else {
                a = {0.f, 0.f, 0.f, 0.f};
            }
            As[lr][lc] = a.x; As[lr][lc + 1] = a.y;
            As[lr][lc + 2] = a.z; As[lr][lc + 3] = a.w;
            int n = n0 + lr;
            int kk = min(k0 + lc, FUSED - 4);
            bool valid;
            const float* wr = wrow_sel(n, va_w1, pol_w, aro_w, valid);
            float4 w = {0.f, 0.f, 0.f, 0.f};
            if (valid) w = *(const float4*)(wr + kk);
            Ws[lr][lc] = w.x; Ws[lr][lc + 1] = w.y;
            Ws[lr][lc + 2] = w.z; Ws[lr][lc + 3] = w.w;
        }
        __syncthreads();
        if (active) {
#pragma unroll
            for (int kk = 0; kk < 32; ++kk) {
                float wv = Ws[tx][kk];
#pragma unroll
                for (int i = 0; i < 4; ++i)
                    acc[i] += As[ty + 8 * i][kk] * wv;
            }
        }
        __syncthreads();
    }
    if (active) {
        int n = n0 + tx;
#pragma unroll
        for (int i = 0; i < 4; ++i) {
            int mm = m0 + ty + 8 * i;
            hdn1p[(size_t)z13 * (B * NOUT) + (size_t)mm * NOUT + n] = acc[i];
        }
    }
}

// ---------------------------------------------------------------------------
// K4: mergectx — T1 XCD placement: grid (NH, B) (XCD i caches wv_h of head i).
// Body otherwise R14 exact.
// ---------------------------------------------------------------------------
__global__ void mergectx_kernel(const float* __restrict__ Op,
                                const float* __restrict__ mlb,
                                const float* __restrict__ wv,
                                const float* __restrict__ bv,
                                float* __restrict__ ctx) {
    int h = blockIdx.x, b = blockIdx.y, t = threadIdx.x;
    float M = -1e30f;
#pragma unroll
    for (int z = 0; z < NSL; ++z)
        M = fmaxf(M, mlb[(((size_t)z * B + b) * NH + h) * 2]);
    float wz[NSL], L = 0.f;
#pragma unroll
    for (int z = 0; z < NSL; ++z) {
        const float* ml = mlb + (((size_t)z * B + b) * NH + h) * 2;
        float e = __expf(ml[0] - M);
        wz[z] = e;
        L += e * ml[1];
    }
    float Li = 1.0f / L;
    __shared__ float wsum[H];
    for (int c = t; c < H; c += 256) {
        float a = 0.f;
#pragma unroll
        for (int z = 0; z < NSL; ++z)
            a += wz[z] * Op[(((size_t)z * B + b) * NH + h) * H + c];
        wsum[c] = a * Li;
    }
    __syncthreads();
    int wave = t >> 6, lane = t & 63;
#pragma unroll
    for (int i = 0; i < 24; ++i) {
        int d = wave * 24 + i;
        const float* wrow = wv + (size_t)(h * DH + d) * H;
        float a = 0.f;
#pragma unroll
        for (int j = 0; j < H / 64; ++j) a += wrow[lane + 64 * j] * wsum[lane + 64 * j];
        for (int off = 32; off; off >>= 1) a += __shfl_xor(a, off);
        if (lane == 0) ctx[b * H + h * DH + d] = a + bv[h * DH + d];
    }
}

// ---------------------------------------------------------------------------
// K5: hdn1-ctx GEMM (R14 exact).
// ---------------------------------------------------------------------------
__global__ __launch_bounds__(256) void k5_hdn1ctx(
        const float* __restrict__ ctx,
        const float* __restrict__ Mbuf,
        float* __restrict__ hdn1p) {
    int z = blockIdx.z;
    int n0 = blockIdx.x * 32, m0 = blockIdx.y * 32;
    int kbase = z * 160;
    __shared__ float As[32][33];
    __shared__ float Ws[32][33];
    int t = threadIdx.x;
    int tx = t & 31, ty = t >> 5;
    int lr = t >> 3, lc = (t & 7) * 4;
    float acc[4] = {0.f, 0.f, 0.f, 0.f};
    for (int k0 = kbase; k0 < kbase + 160; k0 += 32) {
        {
            int bb = m0 + lr;
            int k = k0 + lc;
            float4 a;
            if (k < 768)      a = *(const float4*)(ctx + (size_t)bb * H + k);
            else if (k == 768) a = {1.f, 0.f, 0.f, 0.f};
            else              a = {0.f, 0.f, 0.f, 0.f};
            As[lr][lc] = a.x; As[lr][lc + 1] = a.y;
            As[lr][lc + 2] = a.z; As[lr][lc + 3] = a.w;
        }
        {
            float4 w = *(const float4*)(Mbuf + (size_t)(n0 + lr) * MD + k0 + lc);
            Ws[lr][lc] = w.x; Ws[lr][lc + 1] = w.y;
            Ws[lr][lc + 2] = w.z; Ws[lr][lc + 3] = w.w;
        }
        __syncthreads();
#pragma unroll
        for (int kk = 0; kk < 32; ++kk) {
            float wv = Ws[tx][kk];
#pragma unroll
            for (int i = 0; i < 4; ++i)
                acc[i] += As[ty + 8 * i][kk] * wv;
        }
        __syncthreads();
    }
    int n = n0 + tx;
#pragma unroll
    for (int i = 0; i < 4; ++i) {
        int mm = m0 + ty + 8 * i;
        hdn1p[(size_t)(NZ_NOCTX + z) * (B * NOUT) + (size_t)mm * NOUT + n] = acc[i];
    }
}

// ---------------------------------------------------------------------------
// K6: mlp2 (R14 exact).
// ---------------------------------------------------------------------------
__global__ __launch_bounds__(512) void mlp2_kernel(
        const float* __restrict__ hdn1p,
        const float* __restrict__ va_b1,
        const float* __restrict__ va_w2,
        const float* __restrict__ va_b2,
        const float* __restrict__ va_w3,
        const float* __restrict__ va_b3,
        const float* __restrict__ pol_b,
        const float* __restrict__ aro_b,
        float* __restrict__ out) {
    int b = blockIdx.x, t = threadIdx.x;
    int wave = t >> 6, lane = t & 63;
    __shared__ float hsS[512];
    __shared__ float h2S[128];
    {
        float s = 0.f;
#pragma unroll
        for (int z = 0; z < NZTOT; ++z)
            s += hdn1p[(size_t)z * (B * NOUT) + (size_t)b * NOUT + t];
        hsS[t] = gelu(s + va_b1[t]);
    }
    if (t < 6) {
        float s = 0.f;
#pragma unroll
        for (int z = 0; z < NZTOT; ++z)
            s += hdn1p[(size_t)z * (B * NOUT) + (size_t)b * NOUT + 512 + t];
        if (t < 3) out[256 + b * 3 + t]       = s + pol_b[t];
        else       out[640 + b * 3 + (t - 3)] = s + aro_b[t - 3];
    }
    __syncthreads();
#pragma unroll
    for (int i = 0; i < 16; ++i) {
        int n = wave * 16 + i;
        float a = 0.f;
#pragma unroll
        for (int j = 0; j < 8; ++j) {
            int k = lane + 64 * j;
            a += hsS[k] * va_w2[(size_t)n * 512 + k];
        }
        for (int off = 32; off; off >>= 1) a += __shfl_xor(a, off);
        if (lane == 0) h2S[n] = gelu(a + va_b2[n]);
    }
    __syncthreads();
    if (wave < 2) {
        float a = h2S[lane] * va_w3[wave * 128 + lane]
                + h2S[lane + 64] * va_w3[wave * 128 + lane + 64];
        for (int off = 32; off; off >>= 1) a += __shfl_xor(a, off);
        if (lane == 0) out[b * 2 + wave] = a + va_b3[wave];
    }
}

// ---------------------------------------------------------------------------
extern "C" void kernel_launch(void* const* d_in, const int* in_sizes, int n_in,
                              void* d_out, int out_size, void* d_ws, size_t ws_size,
                              hipStream_t stream) {
    const float* lh    = (const float*)d_in[0];
    const float* aro_f = (const float*)d_in[1];
    const int*   sep1  = (const int*)d_in[2];
    const int*   sep2  = (const int*)d_in[3];
    const float* in_w  = (const float*)d_in[4];
    const float* in_b  = (const float*)d_in[5];
    const float* out_w = (const float*)d_in[6];
    const float* out_b = (const float*)d_in[7];
    const float* ln_g  = (const float*)d_in[8];
    const float* ln_b  = (const float*)d_in[9];
    const float* va_w1 = (const float*)d_in[10];
    const float* va_b1 = (const float*)d_in[11];
    const float* va_w2 = (const float*)d_in[12];
    const float* va_b2 = (const float*)d_in[13];
    const float* va_w3 = (const float*)d_in[14];
    const float* va_b3 = (const float*)d_in[15];
    const float* pol_w = (const float*)d_in[16];
    const float* pol_b = (const float*)d_in[17];
    const float* aro_w = (const float*)d_in[18];
    const float* aro_b = (const float*)d_in[19];
    float* out = (float*)d_out;

    float* ws = (float*)d_ws;
    float* aspp   = ws;                              // ASL*B*H
    float* aspq   = aspp + ASL * B * H;              // B*H
    float* Ubuf   = aspq + B * H;                    // B*NH*H
    float* Opb    = Ubuf + B * NH * H;               // NSL*B*NH*H
    float* mlbuf  = Opb + (size_t)NSL * B * NH * H;  // NSL*B*NH*2
    float* ctx    = mlbuf + NSL * B * NH * 2;        // B*H
    float* Mbuf   = ctx + B * H;                     // 544*MD
    float* hdn1p  = Mbuf + NOUT * MD;                // 18*B*NOUT

    const float* wq = in_w;
    const float* wk = in_w + H * H;
    const float* wv = in_w + 2 * H * H;
    const float* bq = in_b;
    const float* bv = in_b + 2 * H;

    // K1: aspq partials + M = W'_mid @ [out_w | out_b] (hetero)
    k1_aspq_m<<<B * ASL + MTILES, 256, 0, stream>>>(
        lh, sep1, sep2, va_w1, pol_w, aro_w, out_w, out_b, aspp, Mbuf);
    // K2: qu (T1: grid (NH, B) -> per-XCD head-slice L2 residency)
    qu_kernel<<<dim3(NH, B), 256, 0, stream>>>(aspp, sep1, sep2, wq, bq, wk,
                                               aspq, Ubuf);
    // K3: flash (R14 single-buffer) + hdn1-noctx tiles (hetero)
    k3_flash_hdn1<<<B * NSL + HTILES, 512, 0, stream>>>(
        lh, Ubuf, sep1, aspq, aro_f, ln_g, ln_b,
        va_w1, pol_w, aro_w, Opb, mlbuf, hdn1p);
    // K4: mergectx (T1: grid (NH, B))
    mergectx_kernel<<<dim3(NH, B), 256, 0, stream>>>(Opb, mlbuf, wv, bv, ctx);
    // K5: hdn1-ctx via M (K=800, split 5)
    k5_hdn1ctx<<<dim3(17, 4, NZ_CTX), 256, 0, stream>>>(ctx, Mbuf, hdn1p);
    // K6: mlp2
    mlp2_kernel<<<B, 512, 0, stream>>>(hdn1p, va_b1, va_w2, va_b2,
                                       va_w3, va_b3, pol_b, aro_b, out);
}

// Round 17
// 214.349 us; speedup vs baseline: 1.0709x; 1.0281x over previous
//
#include <hip/hip_runtime.h>
#include <hip/hip_bf16.h>
#include <math.h>

#define B 128
#define S 1024
#define H 768
#define NH 8
#define DH 96
#define FUSED 2312
#define KCHUNK 128
#define NOUT 544             // 512 hdn1 + 3 pol + 3 aro + pad
#define MD 800               // M buffer row stride (768 + bias col + pad)
#define NZ_NOCTX 13          // z in {0..5, 12..18}
#define NZ_CTX 5             // K=800 in 5 chunks of 160
#define NZTOT 18
#define ASL 8                // aspq slices
#define NSL 16               // flash slices per sample (R17: 8 -> 16)
#define FCH 16               // rows per flash chunk
#define SCALE 0.10206207261596575f  // 1/sqrt(96)
#define GELU_C 0.70710678118654752f

#define MTILES (17 * 25)     // M-GEMM tile jobs (n-tiles x d-tiles)
#define HTILES (NZ_NOCTX * 4 * 17)  // hdn1-noctx tile jobs = 884

__device__ __forceinline__ float dot4(float4 a, float4 b) {
    return a.x * b.x + a.y * b.y + a.z * b.z + a.w * b.w;
}
__device__ __forceinline__ float gelu(float x) {
    return 0.5f * x * (1.0f + erff(x * GELU_C));
}

// row pointer into the virtual [544][2312] W' (va_w1 | pol_w | aro_w | 0)
__device__ __forceinline__ const float* wrow_sel(int n, const float* va_w1,
                                                 const float* pol_w,
                                                 const float* aro_w,
                                                 bool& valid) {
    valid = true;
    if (n < 512) return va_w1 + (size_t)n * FUSED;
    if (n < 515) return pol_w + (size_t)(n - 512) * FUSED;
    if (n < 518) return aro_w + (size_t)(n - 515) * FUSED;
    valid = false;
    return va_w1;
}

// ---------------------------------------------------------------------------
// K1 hetero: bid<1024 -> aspq partial; else -> M-GEMM tile (R14 exact).
// ---------------------------------------------------------------------------
__global__ __launch_bounds__(256) void k1_aspq_m(
        const float* __restrict__ lh,
        const int* __restrict__ sep1,
        const int* __restrict__ sep2,
        const float* __restrict__ va_w1,
        const float* __restrict__ pol_w,
        const float* __restrict__ aro_w,
        const float* __restrict__ out_w,
        const float* __restrict__ out_b,
        float* __restrict__ aspp,
        float* __restrict__ Mbuf) {
    int bid = blockIdx.x, t = threadIdx.x;
    if (bid < B * ASL) {
        if (t >= 192) return;
        int b = bid >> 3, z = bid & 7;
        int s1 = sep1[b], s2 = sep2[b];
        int lo, hi;
        if (s2 > s1 + 1) { lo = s1 + 1; hi = s2; } else { lo = 0; hi = 1; }
        const float* base = lh + ((size_t)b * S) * H + 4 * t;
        float4 a = {0.f, 0.f, 0.f, 0.f};
        for (int s = lo + z; s < hi; s += ASL) {
            float4 r = *(const float4*)(base + (size_t)s * H);
            a.x += r.x; a.y += r.y; a.z += r.z; a.w += r.w;
        }
        *(float4*)(aspp + (size_t)z * (B * H) + b * H + 4 * t) = a;
        return;
    }
    // ---- M-GEMM tile ----
    int j = bid - B * ASL;            // 0..424
    int n0 = (j / 25) * 32, d0 = (j % 25) * 32;
    __shared__ float As[32][33];
    __shared__ float Ws[32][33];
    int tx = t & 31, ty = t >> 5;
    int lr = t >> 3, lc = (t & 7) * 4;
    float acc[4] = {0.f, 0.f, 0.f, 0.f};
    for (int k0 = 0; k0 < H; k0 += 32) {
        {
            int n = n0 + lr;
            bool valid;
            const float* wr = wrow_sel(n, va_w1, pol_w, aro_w, valid);
            float4 a = {0.f, 0.f, 0.f, 0.f};
            if (valid) a = *(const float4*)(wr + H + k0 + lc);
            As[lr][lc] = a.x; As[lr][lc + 1] = a.y;
            As[lr][lc + 2] = a.z; As[lr][lc + 3] = a.w;
        }
        {
            int c = k0 + lr;
            float4 w;
            if (d0 < H) {
                w = *(const float4*)(out_w + (size_t)c * H + d0 + lc);
            } else {
                w.x = (lc == 0) ? out_b[c] : 0.f;
                w.y = 0.f; w.z = 0.f; w.w = 0.f;
            }
            Ws[lc][lr] = w.x; Ws[lc + 1][lr] = w.y;
            Ws[lc + 2][lr] = w.z; Ws[lc + 3][lr] = w.w;
        }
        __syncthreads();
#pragma unroll
        for (int kk = 0; kk < 32; ++kk) {
            float wv = Ws[tx][kk];
#pragma unroll
            for (int i = 0; i < 4; ++i)
                acc[i] += As[ty + 8 * i][kk] * wv;
        }
        __syncthreads();
    }
#pragma unroll
    for (int i = 0; i < 4; ++i)
        Mbuf[(size_t)(n0 + ty + 8 * i) * MD + d0 + tx] = acc[i];
}

// ---------------------------------------------------------------------------
// K2: qu (R16 exact; T1 grid (NH, B)).
// ---------------------------------------------------------------------------
__global__ void qu_kernel(const float* __restrict__ aspp,
                          const int* __restrict__ sep1,
                          const int* __restrict__ sep2,
                          const float* __restrict__ wq,
                          const float* __restrict__ bq,
                          const float* __restrict__ wk,
                          float* __restrict__ aspq,
                          float* __restrict__ U) {
    int h = blockIdx.x, b = blockIdx.y, t = threadIdx.x;
    int s1 = sep1[b], s2 = sep2[b];
    int lo, hi;
    if (s2 > s1 + 1) { lo = s1 + 1; hi = s2; } else { lo = 0; hi = 1; }
    float inv = 1.0f / (float)(hi - lo);
    __shared__ float aq[H];
    __shared__ float qh[DH];
    for (int c = t; c < H; c += 256) {
        float a = 0.f;
#pragma unroll
        for (int z = 0; z < ASL; ++z)
            a += aspp[(size_t)z * (B * H) + b * H + c];
        a *= inv;
        aq[c] = a;
        if (h == 0) aspq[b * H + c] = a;
    }
    __syncthreads();
    int wave = t >> 6, lane = t & 63;
#pragma unroll
    for (int i = 0; i < 24; ++i) {
        int d = wave * 24 + i;
        const float* wrow = wq + (size_t)(h * DH + d) * H;
        float a = 0.f;
#pragma unroll
        for (int j = 0; j < H / 64; ++j) a += wrow[lane + 64 * j] * aq[lane + 64 * j];
        for (int off = 32; off; off >>= 1) a += __shfl_xor(a, off);
        if (lane == 0) qh[d] = a + bq[h * DH + d];
    }
    __syncthreads();
    if (t < 192) {
        float4 u = {0.f, 0.f, 0.f, 0.f};
        for (int d = 0; d < DH; ++d) {
            float qd = qh[d];
            float4 w = *(const float4*)(wk + (size_t)(h * DH + d) * H + 4 * t);
            u.x += qd * w.x; u.y += qd * w.y;
            u.z += qd * w.z; u.w += qd * w.w;
        }
        *(float4*)(U + ((size_t)b * NH + h) * H + 4 * t) = u;
    }
}

// ---------------------------------------------------------------------------
// K3 hetero: bid < B*NSL -> flash (single-buffer, NSL=16 slices);
//            else       -> hdn1-noctx tile (R14 exact).
// ---------------------------------------------------------------------------
__global__ __launch_bounds__(512) void k3_flash_hdn1(
        const float* __restrict__ lhg,
        const float* __restrict__ U,
        const int* __restrict__ sep1,
        const float* __restrict__ aspq,
        const float* __restrict__ aro_f,
        const float* __restrict__ ln_g,
        const float* __restrict__ ln_b,
        const float* __restrict__ va_w1,
        const float* __restrict__ pol_w,
        const float* __restrict__ aro_w,
        float* __restrict__ Op,     // [NSL][B][NH][H]
        float* __restrict__ mlb,    // [NSL][B][NH][2]
        float* __restrict__ hdn1p) {// [NZTOT][B][NOUT]
    __shared__ float smem[FCH * H];   // 48 KB (overlaid)
    int bid = blockIdx.x, t = threadIdx.x;

    if (bid < B * NSL) {
        int b = bid >> 4, z = bid & 15;
        int wave = t >> 6, lane = t & 63;
        int s1 = sep1[b];
        int tlo = (s1 > 1) ? 1 : 0;
        int thi = (s1 > 1) ? s1 : 1;
        int span = thi - tlo;
        int nrows = (span > z) ? ((span - z - 1) / NSL + 1) : 0;
        float (*lhs)[H] = (float(*)[H])smem;

        const float4* Uh = (const float4*)(U + ((size_t)b * NH + wave) * H);
        float4 u0 = Uh[lane], u1 = Uh[lane + 64], u2 = Uh[lane + 128];
        float4 O0 = {0.f, 0.f, 0.f, 0.f}, O1 = O0, O2 = O0;
        float m = -1e30f, l = 0.f;
        int rid = t >> 5, cid = t & 31;

        for (int j0 = 0; j0 < nrows; j0 += FCH) {
            int nv = min(FCH, nrows - j0);
            if (rid < nv) {
                int sg = tlo + z + NSL * (j0 + rid);
                const float4* row = (const float4*)(lhg + ((size_t)b * S + sg) * H);
                float4* dst = (float4*)lhs[rid];
#pragma unroll
                for (int k = 0; k < 6; ++k) dst[cid + 32 * k] = row[cid + 32 * k];
            }
            __syncthreads();
            for (int r = 0; r < nv; ++r) {
                const float4* xr = (const float4*)lhs[r];
                float4 x0 = xr[lane], x1 = xr[lane + 64], x2 = xr[lane + 128];
                float s = dot4(u0, x0) + dot4(u1, x1) + dot4(u2, x2);
                for (int off = 32; off; off >>= 1) s += __shfl_xor(s, off);
                s *= SCALE;
                if (s <= m) {
                    float p = __expf(s - m);
                    l += p;
                    O0.x += p * x0.x; O0.y += p * x0.y; O0.z += p * x0.z; O0.w += p * x0.w;
                    O1.x += p * x1.x; O1.y += p * x1.y; O1.z += p * x1.z; O1.w += p * x1.w;
                    O2.x += p * x2.x; O2.y += p * x2.y; O2.z += p * x2.z; O2.w += p * x2.w;
                } else {
                    float c = __expf(m - s);
                    m = s;
                    l = l * c + 1.0f;
                    O0.x = O0.x * c + x0.x; O0.y = O0.y * c + x0.y;
                    O0.z = O0.z * c + x0.z; O0.w = O0.w * c + x0.w;
                    O1.x = O1.x * c + x1.x; O1.y = O1.y * c + x1.y;
                    O1.z = O1.z * c + x1.z; O1.w = O1.w * c + x1.w;
                    O2.x = O2.x * c + x2.x; O2.y = O2.y * c + x2.y;
                    O2.z = O2.z * c + x2.z; O2.w = O2.w * c + x2.w;
                }
            }
            __syncthreads();
        }
        float4* Ob = (float4*)(Op + (((size_t)z * B + b) * NH + wave) * H);
        Ob[lane] = O0; Ob[lane + 64] = O1; Ob[lane + 128] = O2;
        if (lane == 0) {
            float* ml = mlb + ((size_t)z * B + b) * NH * 2;
            ml[2 * wave]     = m;
            ml[2 * wave + 1] = l;
        }
        return;
    }

    // ---- hdn1-noctx tile (256 active threads; all 512 hit barriers) ----
    int j = bid - B * NSL;            // 0..883
    int z13 = j / 68, rem = j % 68;
    int z = (z13 < 6) ? z13 : z13 + 6;          // {0..5, 12..18}
    int m0 = (rem / 17) * 32, n0 = (rem % 17) * 32;
    int kbase = z * KCHUNK;
    float (*As)[33] = (float(*)[33])smem;
    float (*Ws)[33] = (float(*)[33])(smem + 32 * 33);
    int tx = t & 31, ty = t >> 5;
    int lr = t >> 3, lc = (t & 7) * 4;
    float acc[4] = {0.f, 0.f, 0.f, 0.f};
    bool active = (t < 256);
    for (int k0 = kbase; k0 < kbase + KCHUNK; k0 += 32) {
        if (active) {
            int bb = m0 + lr;
            int k = k0 + lc;
            float4 a;
            if (k < 768) {
                a = *(const float4*)(lhg + (size_t)bb * S * H + k);
            } else if (k < 2304) {   // only aspq region reachable (z>=12)
                a = *(const float4*)(aspq + (size_t)bb * H + (k - 1536));
            } else if (k < FUSED) {
                const float* af = aro_f + bb * 8;
                float mu = 0.f;
#pragma unroll
                for (int jj = 0; jj < 8; ++jj) mu += af[jj];
                mu *= 0.125f;
                float var = 0.f;
#pragma unroll
                for (int jj = 0; jj < 8; ++jj) { float d = af[jj] - mu; var += d * d; }
                var *= 0.125f;
                float rs = rsqrtf(var + 1e-5f);
                int c = k - 2304;
                a.x = (af[c]     - mu) * rs * ln_g[c]     + ln_b[c];
                a.y = (af[c + 1] - mu) * rs * ln_g[c + 1] + ln_b[c + 1];
                a.z = (af[c + 2] - mu) * rs * ln_g[c + 2] + ln_b[c + 2];
                a.w = (af[c + 3] - mu) * rs * ln_g[c + 3] + ln_b[c + 3];
            } else {
                a = {0.f, 0.f, 0.f, 0.f};
            }
            As[lr][lc] = a.x; As[lr][lc + 1] = a.y;
            As[lr][lc + 2] = a.z; As[lr][lc + 3] = a.w;
            int n = n0 + lr;
            int kk = min(k0 + lc, FUSED - 4);
            bool valid;
            const float* wr = wrow_sel(n, va_w1, pol_w, aro_w, valid);
            float4 w = {0.f, 0.f, 0.f, 0.f};
            if (valid) w = *(const float4*)(wr + kk);
            Ws[lr][lc] = w.x; Ws[lr][lc + 1] = w.y;
            Ws[lr][lc + 2] = w.z; Ws[lr][lc + 3] = w.w;
        }
        __syncthreads();
        if (active) {
#pragma unroll
            for (int kk = 0; kk < 32; ++kk) {
                float wv = Ws[tx][kk];
#pragma unroll
                for (int i = 0; i < 4; ++i)
                    acc[i] += As[ty + 8 * i][kk] * wv;
            }
        }
        __syncthreads();
    }
    if (active) {
        int n = n0 + tx;
#pragma unroll
        for (int i = 0; i < 4; ++i) {
            int mm = m0 + ty + 8 * i;
            hdn1p[(size_t)z13 * (B * NOUT) + (size_t)mm * NOUT + n] = acc[i];
        }
    }
}

// ---------------------------------------------------------------------------
// K4: mergectx (T1 grid (NH, B)); merges NSL=16 slices.
// ---------------------------------------------------------------------------
__global__ void mergectx_kernel(const float* __restrict__ Op,
                                const float* __restrict__ mlb,
                                const float* __restrict__ wv,
                                const float* __restrict__ bv,
                                float* __restrict__ ctx) {
    int h = blockIdx.x, b = blockIdx.y, t = threadIdx.x;
    float M = -1e30f;
#pragma unroll
    for (int z = 0; z < NSL; ++z)
        M = fmaxf(M, mlb[(((size_t)z * B + b) * NH + h) * 2]);
    float wz[NSL], L = 0.f;
#pragma unroll
    for (int z = 0; z < NSL; ++z) {
        const float* ml = mlb + (((size_t)z * B + b) * NH + h) * 2;
        float e = __expf(ml[0] - M);
        wz[z] = e;
        L += e * ml[1];
    }
    float Li = 1.0f / L;
    __shared__ float wsum[H];
    for (int c = t; c < H; c += 256) {
        float a = 0.f;
#pragma unroll
        for (int z = 0; z < NSL; ++z)
            a += wz[z] * Op[(((size_t)z * B + b) * NH + h) * H + c];
        wsum[c] = a * Li;
    }
    __syncthreads();
    int wave = t >> 6, lane = t & 63;
#pragma unroll
    for (int i = 0; i < 24; ++i) {
        int d = wave * 24 + i;
        const float* wrow = wv + (size_t)(h * DH + d) * H;
        float a = 0.f;
#pragma unroll
        for (int j = 0; j < H / 64; ++j) a += wrow[lane + 64 * j] * wsum[lane + 64 * j];
        for (int off = 32; off; off >>= 1) a += __shfl_xor(a, off);
        if (lane == 0) ctx[b * H + h * DH + d] = a + bv[h * DH + d];
    }
}

// ---------------------------------------------------------------------------
// K5: hdn1-ctx GEMM (R14 exact).
// ---------------------------------------------------------------------------
__global__ __launch_bounds__(256) void k5_hdn1ctx(
        const float* __restrict__ ctx,
        const float* __restrict__ Mbuf,
        float* __restrict__ hdn1p) {
    int z = blockIdx.z;
    int n0 = blockIdx.x * 32, m0 = blockIdx.y * 32;
    int kbase = z * 160;
    __shared__ float As[32][33];
    __shared__ float Ws[32][33];
    int t = threadIdx.x;
    int tx = t & 31, ty = t >> 5;
    int lr = t >> 3, lc = (t & 7) * 4;
    float acc[4] = {0.f, 0.f, 0.f, 0.f};
    for (int k0 = kbase; k0 < kbase + 160; k0 += 32) {
        {
            int bb = m0 + lr;
            int k = k0 + lc;
            float4 a;
            if (k < 768)      a = *(const float4*)(ctx + (size_t)bb * H + k);
            else if (k == 768) a = {1.f, 0.f, 0.f, 0.f};
            else              a = {0.f, 0.f, 0.f, 0.f};
            As[lr][lc] = a.x; As[lr][lc + 1] = a.y;
            As[lr][lc + 2] = a.z; As[lr][lc + 3] = a.w;
        }
        {
            float4 w = *(const float4*)(Mbuf + (size_t)(n0 + lr) * MD + k0 + lc);
            Ws[lr][lc] = w.x; Ws[lr][lc + 1] = w.y;
            Ws[lr][lc + 2] = w.z; Ws[lr][lc + 3] = w.w;
        }
        __syncthreads();
#pragma unroll
        for (int kk = 0; kk < 32; ++kk) {
            float wv = Ws[tx][kk];
#pragma unroll
            for (int i = 0; i < 4; ++i)
                acc[i] += As[ty + 8 * i][kk] * wv;
        }
        __syncthreads();
    }
    int n = n0 + tx;
#pragma unroll
    for (int i = 0; i < 4; ++i) {
        int mm = m0 + ty + 8 * i;
        hdn1p[(size_t)(NZ_NOCTX + z) * (B * NOUT) + (size_t)mm * NOUT + n] = acc[i];
    }
}

// ---------------------------------------------------------------------------
// K6: mlp2 (R14 exact).
// ---------------------------------------------------------------------------
__global__ __launch_bounds__(512) void mlp2_kernel(
        const float* __restrict__ hdn1p,
        const float* __restrict__ va_b1,
        const float* __restrict__ va_w2,
        const float* __restrict__ va_b2,
        const float* __restrict__ va_w3,
        const float* __restrict__ va_b3,
        const float* __restrict__ pol_b,
        const float* __restrict__ aro_b,
        float* __restrict__ out) {
    int b = blockIdx.x, t = threadIdx.x;
    int wave = t >> 6, lane = t & 63;
    __shared__ float hsS[512];
    __shared__ float h2S[128];
    {
        float s = 0.f;
#pragma unroll
        for (int z = 0; z < NZTOT; ++z)
            s += hdn1p[(size_t)z * (B * NOUT) + (size_t)b * NOUT + t];
        hsS[t] = gelu(s + va_b1[t]);
    }
    if (t < 6) {
        float s = 0.f;
#pragma unroll
        for (int z = 0; z < NZTOT; ++z)
            s += hdn1p[(size_t)z * (B * NOUT) + (size_t)b * NOUT + 512 + t];
        if (t < 3) out[256 + b * 3 + t]       = s + pol_b[t];
        else       out[640 + b * 3 + (t - 3)] = s + aro_b[t - 3];
    }
    __syncthreads();
#pragma unroll
    for (int i = 0; i < 16; ++i) {
        int n = wave * 16 + i;
        float a = 0.f;
#pragma unroll
        for (int j = 0; j < 8; ++j) {
            int k = lane + 64 * j;
            a += hsS[k] * va_w2[(size_t)n * 512 + k];
        }
        for (int off = 32; off; off >>= 1) a += __shfl_xor(a, off);
        if (lane == 0) h2S[n] = gelu(a + va_b2[n]);
    }
    __syncthreads();
    if (wave < 2) {
        float a = h2S[lane] * va_w3[wave * 128 + lane]
                + h2S[lane + 64] * va_w3[wave * 128 + lane + 64];
        for (int off = 32; off; off >>= 1) a += __shfl_xor(a, off);
        if (lane == 0) out[b * 2 + wave] = a + va_b3[wave];
    }
}

// ---------------------------------------------------------------------------
extern "C" void kernel_launch(void* const* d_in, const int* in_sizes, int n_in,
                              void* d_out, int out_size, void* d_ws, size_t ws_size,
                              hipStream_t stream) {
    const float* lh    = (const float*)d_in[0];
    const float* aro_f = (const float*)d_in[1];
    const int*   sep1  = (const int*)d_in[2];
    const int*   sep2  = (const int*)d_in[3];
    const float* in_w  = (const float*)d_in[4];
    const float* in_b  = (const float*)d_in[5];
    const float* out_w = (const float*)d_in[6];
    const float* out_b = (const float*)d_in[7];
    const float* ln_g  = (const float*)d_in[8];
    const float* ln_b  = (const float*)d_in[9];
    const float* va_w1 = (const float*)d_in[10];
    const float* va_b1 = (const float*)d_in[11];
    const float* va_w2 = (const float*)d_in[12];
    const float* va_b2 = (const float*)d_in[13];
    const float* va_w3 = (const float*)d_in[14];
    const float* va_b3 = (const float*)d_in[15];
    const float* pol_w = (const float*)d_in[16];
    const float* pol_b = (const float*)d_in[17];
    const float* aro_w = (const float*)d_in[18];
    const float* aro_b = (const float*)d_in[19];
    float* out = (float*)d_out;

    float* ws = (float*)d_ws;
    float* aspp   = ws;                              // ASL*B*H
    float* aspq   = aspp + ASL * B * H;              // B*H
    float* Ubuf   = aspq + B * H;                    // B*NH*H
    float* Opb    = Ubuf + B * NH * H;               // NSL*B*NH*H (16 slices)
    float* mlbuf  = Opb + (size_t)NSL * B * NH * H;  // NSL*B*NH*2
    float* ctx    = mlbuf + NSL * B * NH * 2;        // B*H
    float* Mbuf   = ctx + B * H;                     // 544*MD
    float* hdn1p  = Mbuf + NOUT * MD;                // 18*B*NOUT

    const float* wq = in_w;
    const float* wk = in_w + H * H;
    const float* wv = in_w + 2 * H * H;
    const float* bq = in_b;
    const float* bv = in_b + 2 * H;

    // K1: aspq partials + M = W'_mid @ [out_w | out_b] (hetero)
    k1_aspq_m<<<B * ASL + MTILES, 256, 0, stream>>>(
        lh, sep1, sep2, va_w1, pol_w, aro_w, out_w, out_b, aspp, Mbuf);
    // K2: qu
    qu_kernel<<<dim3(NH, B), 256, 0, stream>>>(aspp, sep1, sep2, wq, bq, wk,
                                               aspq, Ubuf);
    // K3: flash (NSL=16) + hdn1-noctx tiles (hetero)
    k3_flash_hdn1<<<B * NSL + HTILES, 512, 0, stream>>>(
        lh, Ubuf, sep1, aspq, aro_f, ln_g, ln_b,
        va_w1, pol_w, aro_w, Opb, mlbuf, hdn1p);
    // K4: mergectx (16-slice merge)
    mergectx_kernel<<<dim3(NH, B), 256, 0, stream>>>(Opb, mlbuf, wv, bv, ctx);
    // K5: hdn1-ctx via M (K=800, split 5)
    k5_hdn1ctx<<<dim3(17, 4, NZ_CTX), 256, 0, stream>>>(ctx, Mbuf, hdn1p);
    // K6: mlp2
    mlp2_kernel<<<B, 512, 0, stream>>>(hdn1p, va_b1, va_w2, va_b2,
                                       va_w3, va_b3, pol_b, aro_b, out);
}